// Round 6
// baseline (3890.720 us; speedup 1.0000x reference)
//
#include <hip/hip_runtime.h>

// GRU recurrence, fused persistent kernel (round 6).
// r4/r5 lesson: compiler sinks weight loads (VGPR 128->64), serializing ~56
// L2 hits/step/lane. Fixes:
//  (1) mega-pin asm volatile("" : "+v"(...)) over whole load batches ->
//      compiler cannot sink/remat; ~36-44 loads in flight per wave.
//  (2) ROWS=8, 128 blocks (rows mirrored into both MFMA half-tiles) -> 2x CUs.
//  (3) w_state LDS-resident (phase 2 has zero vmem); 512 thr, (512,2) 256-VGPR cap.

typedef __attribute__((ext_vector_type(8))) short short8;   // 8 x bf16 MFMA frag
typedef __attribute__((ext_vector_type(4))) float f32x4;

constexpr int B_ = 1024, T_ = 128, I_ = 128, H_ = 256, OUT_ = 64;
constexpr int ROWS = 8;         // batch rows per block (mirrored to 16-row tile)
constexpr int NBLK = B_ / ROWS; // 128 blocks

#define DEVI __device__ __forceinline__

DEVI unsigned short f2b(float f) {
    unsigned u = __builtin_bit_cast(unsigned, f);
    u += 0x7fffu + ((u >> 16) & 1u);
    return (unsigned short)(u >> 16);
}
DEVI float sigmoidf_(float x) { float e = __expf(-x); return __fdividef(1.f, 1.f + e); }
DEVI float tanhf_(float x) { float e = __expf(2.f * x); return __fdividef(e - 1.f, e + 1.f); }

DEVI f32x4 ld4(const void* p) { return *reinterpret_cast<const f32x4*>(p); }
DEVI short8 asfrag(f32x4 v) { return __builtin_bit_cast(short8, v); }
DEVI short8 ldg8(const unsigned short* p) {
    return __builtin_bit_cast(short8, *reinterpret_cast<const uint4*>(p));
}
DEVI short8 pack8(f32x4 lo, f32x4 hi) {   // 8 f32 -> bf16 frag
    union { unsigned short s[8]; short8 v; } r;
#pragma unroll
    for (int e = 0; e < 4; ++e) { r.s[e] = f2b(lo[e]); r.s[4 + e] = f2b(hi[e]); }
    return r.v;
}
DEVI f32x4 mfma(short8 a, short8 b, f32x4 c) {
    return __builtin_amdgcn_mfma_f32_16x16x32_bf16(a, b, c, 0, 0, 0);
}

// XOR-swizzled [*][256] bf16 tile: byte ^= (row&7)<<4
DEVI unsigned short* swz(unsigned short* base, int row, int col) {
    int byte = (row * H_ + col) * 2;
    byte ^= (row & 7) << 4;
    return (unsigned short*)((char*)base + byte);
}
DEVI const unsigned short* swzc(const unsigned short* base, int row, int col) {
    int byte = (row * H_ + col) * 2;
    byte ^= (row & 7) << 4;
    return (const unsigned short*)((const char*)base + byte);
}

// mega-pins: force all named frags to be loaded & register-resident here
#define PIN12(A) asm volatile("" : "+v"(A[0]),"+v"(A[1]),"+v"(A[2]),"+v"(A[3]),\
    "+v"(A[4]),"+v"(A[5]),"+v"(A[6]),"+v"(A[7]),"+v"(A[8]),"+v"(A[9]),\
    "+v"(A[10]),"+v"(A[11]))
#define PIN24(A) asm volatile("" : "+v"(A[0]),"+v"(A[1]),"+v"(A[2]),"+v"(A[3]),\
    "+v"(A[4]),"+v"(A[5]),"+v"(A[6]),"+v"(A[7]),"+v"(A[8]),"+v"(A[9]),\
    "+v"(A[10]),"+v"(A[11]),"+v"(A[12]),"+v"(A[13]),"+v"(A[14]),"+v"(A[15]),\
    "+v"(A[16]),"+v"(A[17]),"+v"(A[18]),"+v"(A[19]),"+v"(A[20]),"+v"(A[21]),\
    "+v"(A[22]),"+v"(A[23]))
#define PIN8(A) asm volatile("" : "+v"(A[0]),"+v"(A[1]),"+v"(A[2]),"+v"(A[3]),\
    "+v"(A[4]),"+v"(A[5]),"+v"(A[6]),"+v"(A[7]))

// ---- weight pre-conversion: f32 -> bf16 into d_ws ----
__global__ void cvt_w(const float* __restrict__ src, unsigned short* __restrict__ dst, int n) {
    int i = (blockIdx.x * blockDim.x + threadIdx.x) * 8;
    if (i >= n) return;
    f32x4 lo = ld4(src + i), hi = ld4(src + i + 4);
    union { unsigned short s[8]; uint4 v; } r;
#pragma unroll
    for (int e = 0; e < 4; ++e) { r.s[e] = f2b(lo[e]); r.s[4 + e] = f2b(hi[e]); }
    *reinterpret_cast<uint4*>(dst + i) = r.v;
}

__global__ __launch_bounds__(512, 2) void gru_fused(
    const float* __restrict__ s0,             // [B][H] f32
    const float* __restrict__ a,              // [B][T][I] f32
    const unsigned short* __restrict__ w_ih,  // [3H][I] bf16 (ws)
    const unsigned short* __restrict__ w_hh,  // [3H][H] bf16 (ws)
    const unsigned short* __restrict__ w_rw,  // [OUT][H] bf16 (ws)
    const unsigned short* __restrict__ w_st,  // [H][H] bf16 (ws)
    float* __restrict__ out_r,                // [T][OUT] f32
    float* __restrict__ out_s)                // [B][T][H] f32
{
    __shared__ unsigned short wst_l[H_ * H_];   // 131072 B, swizzled
    __shared__ unsigned short h16[ROWS * H_];   // 4096 B
    __shared__ unsigned short hn16[ROWS * H_];  // 4096 B

    const int tid = threadIdx.x;
    const int w = tid >> 6;       // wave 0..7
    const int l = tid & 63;
    const int m = l & 15;         // MFMA row/col-in-tile
    const int mr = m & 7;         // mirrored batch row
    const int kg = l >> 4;        // k-group
    const int R0 = blockIdx.x * ROWS;
    const int g0 = (2 * w + 0) * 16 + m;   // u=0 column
    const int g1 = (2 * w + 1) * 16 + m;   // u=1 column

    // stage w_state into LDS (once), swizzled
#pragma unroll
    for (int i = 0; i < 16; ++i) {
        const int idx = (tid + i * 512) * 8;
        *reinterpret_cast<uint4*>(swz(wst_l, idx >> 8, idx & 255)) =
            *reinterpret_cast<const uint4*>(w_st + idx);
    }
    // init h16 rows 0..7
    if (tid < 256) {
        const int pr = tid >> 5, pc = (tid & 31) * 8;
        const float* sp = &s0[(size_t)(R0 + pr) * H_ + pc];
        *reinterpret_cast<uint4*>(swz(h16, pr, pc)) =
            __builtin_bit_cast(uint4, pack8(ld4(sp), ld4(sp + 4)));
    }
    // f32 carry in regs (mirrored rows duplicate values)
    float hreg0[4], hreg1[4];
#pragma unroll
    for (int v = 0; v < 4; ++v) {
        hreg0[v] = s0[(size_t)(R0 + ((kg * 4 + v) & 7)) * H_ + g0];
        hreg1[v] = s0[(size_t)(R0 + ((kg * 4 + v) & 7)) * H_ + g1];
    }
    __syncthreads();

    for (int t = 0; t < T_; ++t) {
        // ================= phase 1 =================
        // issue x (8) + wi u0 (12) + wh u0 (24) loads -> 44 in flight
        f32x4 xraw[8], wiA[12], whA[24];
        {
            const float* xr = a + ((size_t)(R0 + mr) * T_ + t) * I_ + kg * 8;
#pragma unroll
            for (int kt = 0; kt < 4; ++kt) {
                xraw[2 * kt]     = ld4(xr + kt * 32);
                xraw[2 * kt + 1] = ld4(xr + kt * 32 + 4);
            }
            const unsigned short* pwi = w_ih + (size_t)g0 * I_ + kg * 8;
#pragma unroll
            for (int kt = 0; kt < 4; ++kt) {
                wiA[kt]     = ld4(pwi + kt * 32);
                wiA[4 + kt] = ld4(pwi + 256 * I_ + kt * 32);
                wiA[8 + kt] = ld4(pwi + 512 * I_ + kt * 32);
            }
            const unsigned short* pwh = w_hh + (size_t)g0 * H_ + kg * 8;
#pragma unroll
            for (int kt = 0; kt < 8; ++kt) {
                whA[kt]      = ld4(pwh + kt * 32);
                whA[8 + kt]  = ld4(pwh + 256 * H_ + kt * 32);
                whA[16 + kt] = ld4(pwh + 512 * H_ + kt * 32);
            }
        }
        short8 ha[8];
#pragma unroll
        for (int kt = 0; kt < 8; ++kt)
            ha[kt] = ldg8(swzc(h16, mr, kt * 32 + kg * 8));

        PIN8(xraw);
        PIN12(wiA);
        short8 xa[4];
#pragma unroll
        for (int kt = 0; kt < 4; ++kt) {
            union { f32x4 f[2]; } t2;  // pack 8 f32 -> bf16
            xa[kt] = pack8(xraw[2 * kt], xraw[2 * kt + 1]);
            (void)t2;
        }

        f32x4 ar = {0,0,0,0}, az = {0,0,0,0}, ani = {0,0,0,0}, anh = {0,0,0,0};
#pragma unroll
        for (int kt = 0; kt < 4; ++kt) {            // x-part u0
            ar  = mfma(xa[kt], asfrag(wiA[kt]),     ar);
            az  = mfma(xa[kt], asfrag(wiA[4 + kt]), az);
            ani = mfma(xa[kt], asfrag(wiA[8 + kt]), ani);
        }
        PIN24(whA);
#pragma unroll
        for (int kt = 0; kt < 8; ++kt) {            // h-part u0
            ar  = mfma(ha[kt], asfrag(whA[kt]),      ar);
            az  = mfma(ha[kt], asfrag(whA[8 + kt]),  az);
            anh = mfma(ha[kt], asfrag(whA[16 + kt]), anh);
        }
        // issue u1 loads while u0 gates compute
        f32x4 wiB[12], whB[24];
        {
            const unsigned short* pwi = w_ih + (size_t)g1 * I_ + kg * 8;
#pragma unroll
            for (int kt = 0; kt < 4; ++kt) {
                wiB[kt]     = ld4(pwi + kt * 32);
                wiB[4 + kt] = ld4(pwi + 256 * I_ + kt * 32);
                wiB[8 + kt] = ld4(pwi + 512 * I_ + kt * 32);
            }
            const unsigned short* pwh = w_hh + (size_t)g1 * H_ + kg * 8;
#pragma unroll
            for (int kt = 0; kt < 8; ++kt) {
                whB[kt]      = ld4(pwh + kt * 32);
                whB[8 + kt]  = ld4(pwh + 256 * H_ + kt * 32);
                whB[16 + kt] = ld4(pwh + 512 * H_ + kt * 32);
            }
        }
        {   // gates u0 -> hn16
#pragma unroll
            for (int v = 0; v < 4; ++v) {
                const float rg = sigmoidf_(ar[v]);
                const float zg = sigmoidf_(az[v]);
                const float ng = tanhf_(ani[v] + rg * anh[v]);
                const float hv = (1.f - zg) * ng + zg * hreg0[v];
                const int row = (kg * 4 + v) & 7;
                if ((kg * 4 + v) < 8) *swz(hn16, row, g0) = f2b(hv);
            }
        }
        PIN12(wiB);
        f32x4 br = {0,0,0,0}, bz = {0,0,0,0}, bni = {0,0,0,0}, bnh = {0,0,0,0};
#pragma unroll
        for (int kt = 0; kt < 4; ++kt) {            // x-part u1
            br  = mfma(xa[kt], asfrag(wiB[kt]),     br);
            bz  = mfma(xa[kt], asfrag(wiB[4 + kt]), bz);
            bni = mfma(xa[kt], asfrag(wiB[8 + kt]), bni);
        }
        PIN24(whB);
#pragma unroll
        for (int kt = 0; kt < 8; ++kt) {            // h-part u1
            br  = mfma(ha[kt], asfrag(whB[kt]),      br);
            bz  = mfma(ha[kt], asfrag(whB[8 + kt]),  bz);
            bnh = mfma(ha[kt], asfrag(whB[16 + kt]), bnh);
        }
#pragma unroll
        for (int v = 0; v < 4; ++v) {               // gates u1 -> hn16
            const float rg = sigmoidf_(br[v]);
            const float zg = sigmoidf_(bz[v]);
            const float ng = tanhf_(bni[v] + rg * bnh[v]);
            const float hv = (1.f - zg) * ng + zg * hreg1[v];
            const int row = (kg * 4 + v) & 7;
            if ((kg * 4 + v) < 8) *swz(hn16, row, g1) = f2b(hv);
        }
        __syncthreads();

        // ================= phase 2 (LDS-only operands) =================
        short8 na[8];
#pragma unroll
        for (int kt = 0; kt < 8; ++kt)
            na[kt] = ldg8(swzc(hn16, mr, kt * 32 + kg * 8));
#pragma unroll
        for (int u = 0; u < 2; ++u) {
            const int j = (u == 0) ? g0 : g1;
            f32x4 acc = {0,0,0,0};
#pragma unroll
            for (int kt = 0; kt < 8; ++kt)
                acc = mfma(na[kt], ldg8(swzc(wst_l, j, kt * 32 + kg * 8)), acc);
#pragma unroll
            for (int v = 0; v < 4; ++v) {
                const float s = sigmoidf_(acc[v]);
                if (u == 0) hreg0[v] = s; else hreg1[v] = s;
                const int rowi = kg * 4 + v;
                if (rowi < 8) {
                    *swz(h16, rowi, j) = f2b(s);
                    out_s[((size_t)(R0 + rowi) * T_ + t) * H_ + j] = s;
                }
            }
        }
        if (blockIdx.x == 0 && w < 4) {  // r_t = sig(h_new[0] @ w_reward^T)
            const int o = w * 16 + m;
            f32x4 accr = {0,0,0,0};
            const unsigned short* p = w_rw + (size_t)o * H_ + kg * 8;
#pragma unroll
            for (int kt = 0; kt < 8; ++kt)
                accr = mfma(na[kt], ldg8(p + kt * 32), accr);
            if (kg == 0)
                out_r[t * OUT_ + o] = sigmoidf_(accr[0]);
        }
        __syncthreads();
    }
}

extern "C" void kernel_launch(void* const* d_in, const int* in_sizes, int n_in,
                              void* d_out, int out_size, void* d_ws, size_t ws_size,
                              hipStream_t stream) {
    const float* s0  = (const float*)d_in[0];
    const float* a   = (const float*)d_in[1];
    const float* wih = (const float*)d_in[2];
    const float* whh = (const float*)d_in[3];
    const float* wrw = (const float*)d_in[4];
    const float* wst = (const float*)d_in[5];

    unsigned short* ws16 = (unsigned short*)d_ws;
    unsigned short* wih16 = ws16;                 // 768*128  = 98304
    unsigned short* whh16 = wih16 + 98304;        // 768*256  = 196608
    unsigned short* wrw16 = whh16 + 196608;       // 64*256   = 16384
    unsigned short* wst16 = wrw16 + 16384;        // 256*256  = 65536

    cvt_w<<<98304  / (256 * 8), 256, 0, stream>>>(wih, wih16, 98304);
    cvt_w<<<196608 / (256 * 8), 256, 0, stream>>>(whh, whh16, 196608);
    cvt_w<<<16384  / (256 * 8), 256, 0, stream>>>(wrw, wrw16, 16384);
    cvt_w<<<65536  / (256 * 8), 256, 0, stream>>>(wst, wst16, 65536);

    float* out = (float*)d_out;
    gru_fused<<<NBLK, 512, 0, stream>>>(s0, a, wih16, whh16, wrw16, wst16,
                                        out, out + (size_t)T_ * OUT_);
}

// Round 7
// 2297.707 us; speedup vs baseline: 1.6933x; 1.6933x over previous
//
#include <hip/hip_runtime.h>

// GRU recurrence, fused persistent kernel (round 7).
// r6 lesson: pinned batches DO pipeline (sustained 904 GB/s) but 128 blocks
// thrash L2 (34% miss -> 3.56 GB HBM). r5 lesson: 64 blocks are L2-friendly
// (325 MB) but VGPR=64 serialized loads. This round:
//   - 64 blocks, 512 thr, (512,2) -> 256 VGPR cap.
//   - w_hh r,z slices REGISTER-RESIDENT across T-loop (32 frags = 128 VGPR,
//     re-pinned each iteration: "+v" loop-carried dep forbids remat).
//   - streamed per step: w_ih (24 frags) + w_hh n-slice (16 frags), pinned.
//   - w_state in LDS (phase 2 vmem-free); h/hn bf16 swizzled LDS.
//   - x(t+1) raw-prefetch issued at top of phase 2.

typedef __attribute__((ext_vector_type(8))) short short8;   // 8 x bf16 MFMA frag
typedef __attribute__((ext_vector_type(4))) float f32x4;

constexpr int B_ = 1024, T_ = 128, I_ = 128, H_ = 256, OUT_ = 64;
constexpr int ROWS = 16;        // batch rows per block
constexpr int NBLK = B_ / ROWS; // 64 blocks

#define DEVI __device__ __forceinline__

DEVI unsigned short f2b(float f) {
    unsigned u = __builtin_bit_cast(unsigned, f);
    u += 0x7fffu + ((u >> 16) & 1u);
    return (unsigned short)(u >> 16);
}
DEVI float sigmoidf_(float x) { float e = __expf(-x); return __fdividef(1.f, 1.f + e); }
DEVI float tanhf_(float x) { float e = __expf(2.f * x); return __fdividef(e - 1.f, e + 1.f); }

DEVI f32x4 ld4(const void* p) { return *reinterpret_cast<const f32x4*>(p); }
DEVI short8 ldg8(const unsigned short* p) {
    return __builtin_bit_cast(short8, *reinterpret_cast<const uint4*>(p));
}
DEVI short8 pack8(f32x4 lo, f32x4 hi) {
    union { unsigned short s[8]; short8 v; } r;
#pragma unroll
    for (int e = 0; e < 4; ++e) { r.s[e] = f2b(lo[e]); r.s[4 + e] = f2b(hi[e]); }
    return r.v;
}
DEVI f32x4 mfma(short8 a, short8 b, f32x4 c) {
    return __builtin_amdgcn_mfma_f32_16x16x32_bf16(a, b, c, 0, 0, 0);
}

// XOR-swizzled [*][256] bf16 tile: byte ^= (row&7)<<4
DEVI unsigned short* swz(unsigned short* base, int row, int col) {
    int byte = (row * H_ + col) * 2;
    byte ^= (row & 7) << 4;
    return (unsigned short*)((char*)base + byte);
}
DEVI const unsigned short* swzc(const unsigned short* base, int row, int col) {
    int byte = (row * H_ + col) * 2;
    byte ^= (row & 7) << 4;
    return (const unsigned short*)((const char*)base + byte);
}

#define PIN8(A) asm volatile("" : "+v"(A[0]),"+v"(A[1]),"+v"(A[2]),"+v"(A[3]),\
    "+v"(A[4]),"+v"(A[5]),"+v"(A[6]),"+v"(A[7]))
#define PIN8O(A) asm volatile("" : "+v"(A[8]),"+v"(A[9]),"+v"(A[10]),"+v"(A[11]),\
    "+v"(A[12]),"+v"(A[13]),"+v"(A[14]),"+v"(A[15]))
#define PIN4(A) asm volatile("" : "+v"(A[0]),"+v"(A[1]),"+v"(A[2]),"+v"(A[3]))

// ---- weight pre-conversion: f32 -> bf16 into d_ws ----
__global__ void cvt_w(const float* __restrict__ src, unsigned short* __restrict__ dst, int n) {
    int i = (blockIdx.x * blockDim.x + threadIdx.x) * 8;
    if (i >= n) return;
    f32x4 lo = ld4(src + i), hi = ld4(src + i + 4);
    union { unsigned short s[8]; uint4 v; } r;
#pragma unroll
    for (int e = 0; e < 4; ++e) { r.s[e] = f2b(lo[e]); r.s[4 + e] = f2b(hi[e]); }
    *reinterpret_cast<uint4*>(dst + i) = r.v;
}

__global__ __launch_bounds__(512, 2) void gru_fused(
    const float* __restrict__ s0,             // [B][H] f32
    const float* __restrict__ a,              // [B][T][I] f32
    const unsigned short* __restrict__ w_ih,  // [3H][I] bf16 (ws)
    const unsigned short* __restrict__ w_hh,  // [3H][H] bf16 (ws)
    const unsigned short* __restrict__ w_rw,  // [OUT][H] bf16 (ws)
    const unsigned short* __restrict__ w_st,  // [H][H] bf16 (ws)
    float* __restrict__ out_r,                // [T][OUT] f32
    float* __restrict__ out_s)                // [B][T][H] f32
{
    __shared__ unsigned short wst_l[H_ * H_];   // 131072 B, swizzled
    __shared__ unsigned short h16[ROWS * H_];   // 8192 B
    __shared__ unsigned short hn16[ROWS * H_];  // 8192 B

    const int tid = threadIdx.x;
    const int w = tid >> 6;       // wave 0..7
    const int l = tid & 63;
    const int m = l & 15;
    const int kg = l >> 4;
    const int R0 = blockIdx.x * ROWS;
    const int g0 = (2 * w + 0) * 16 + m;   // this wave's two column tiles
    const int g1 = (2 * w + 1) * 16 + m;

    // stage w_state into LDS, swizzled (8192 uint4 / 512 thr = 16 each)
#pragma unroll
    for (int i = 0; i < 16; ++i) {
        const int idx = (tid + i * 512) * 8;
        *reinterpret_cast<uint4*>(swz(wst_l, idx >> 8, idx & 255)) =
            *reinterpret_cast<const uint4*>(w_st + idx);
    }
    // init h16 (16 rows x 256 cols bf16)
    {
        const int pr = tid >> 5, pc = (tid & 31) * 8;
        const float* sp = &s0[(size_t)(R0 + pr) * H_ + pc];
        *reinterpret_cast<uint4*>(swz(h16, pr, pc)) =
            __builtin_bit_cast(uint4, pack8(ld4(sp), ld4(sp + 4)));
    }
    // f32 carry in regs
    float hreg0[4], hreg1[4];
#pragma unroll
    for (int v = 0; v < 4; ++v) {
        hreg0[v] = s0[(size_t)(R0 + kg * 4 + v) * H_ + g0];
        hreg1[v] = s0[(size_t)(R0 + kg * 4 + v) * H_ + g1];
    }

    // RESIDENT: w_hh r-slice and z-slice fragments (loop-invariant, 128 VGPR)
    short8 whhR[16], whhZ[16];   // [u*8 + kt]
#pragma unroll
    for (int u = 0; u < 2; ++u) {
        const int g = (u == 0) ? g0 : g1;
#pragma unroll
        for (int kt = 0; kt < 8; ++kt) {
            whhR[u * 8 + kt] = ldg8(w_hh + (size_t)(g)       * H_ + kt * 32 + kg * 8);
            whhZ[u * 8 + kt] = ldg8(w_hh + (size_t)(g + 256) * H_ + kt * 32 + kg * 8);
        }
    }
    __syncthreads();

    // x fragments for t=0
    short8 xa[4];
    {
        const float* xr = a + (size_t)(R0 + m) * T_ * I_ + kg * 8;
#pragma unroll
        for (int kt = 0; kt < 4; ++kt)
            xa[kt] = pack8(ld4(xr + kt * 32), ld4(xr + kt * 32 + 4));
    }

    for (int t = 0; t < T_; ++t) {
        // re-pin residents: opaque loop-carried dep -> cannot be remat'd
        PIN8(whhR); PIN8O(whhR); PIN8(whhZ); PIN8O(whhZ);
        PIN4(xa);

        // ---------------- phase 1: x-part (streamed w_ih) ----------------
        f32x4 ar0 = {0,0,0,0}, az0 = {0,0,0,0}, ani0 = {0,0,0,0};
        f32x4 ar1 = {0,0,0,0}, az1 = {0,0,0,0}, ani1 = {0,0,0,0};
        {
            const unsigned short* p0 = w_ih + (size_t)g0 * I_ + kg * 8;
            const unsigned short* p1 = w_ih + (size_t)g1 * I_ + kg * 8;
            short8 wb[8];
            // gate r
#pragma unroll
            for (int kt = 0; kt < 4; ++kt) {
                wb[kt]     = ldg8(p0 + kt * 32);
                wb[4 + kt] = ldg8(p1 + kt * 32);
            }
            PIN8(wb);
#pragma unroll
            for (int kt = 0; kt < 4; ++kt) {
                ar0 = mfma(xa[kt], wb[kt],     ar0);
                ar1 = mfma(xa[kt], wb[4 + kt], ar1);
            }
            // gate z
#pragma unroll
            for (int kt = 0; kt < 4; ++kt) {
                wb[kt]     = ldg8(p0 + 256 * I_ + kt * 32);
                wb[4 + kt] = ldg8(p1 + 256 * I_ + kt * 32);
            }
            PIN8(wb);
#pragma unroll
            for (int kt = 0; kt < 4; ++kt) {
                az0 = mfma(xa[kt], wb[kt],     az0);
                az1 = mfma(xa[kt], wb[4 + kt], az1);
            }
            // gate n (input part)
#pragma unroll
            for (int kt = 0; kt < 4; ++kt) {
                wb[kt]     = ldg8(p0 + 512 * I_ + kt * 32);
                wb[4 + kt] = ldg8(p1 + 512 * I_ + kt * 32);
            }
            PIN8(wb);
#pragma unroll
            for (int kt = 0; kt < 4; ++kt) {
                ani0 = mfma(xa[kt], wb[kt],     ani0);
                ani1 = mfma(xa[kt], wb[4 + kt], ani1);
            }
        }

        // ---------------- phase 1: h-part (resident r,z + streamed n) ----
        f32x4 anh0 = {0,0,0,0}, anh1 = {0,0,0,0};
        {
            short8 wn[16];   // streamed w_hh n-slice, both cols
#pragma unroll
            for (int kt = 0; kt < 8; ++kt) {
                wn[kt]     = ldg8(w_hh + (size_t)(512 + g0) * H_ + kt * 32 + kg * 8);
                wn[8 + kt] = ldg8(w_hh + (size_t)(512 + g1) * H_ + kt * 32 + kg * 8);
            }
            PIN8(wn); PIN8O(wn);
#pragma unroll
            for (int kt = 0; kt < 8; ++kt) {
                const short8 hv = ldg8(swzc(h16, m, kt * 32 + kg * 8));
                ar0  = mfma(hv, whhR[kt],     ar0);
                az0  = mfma(hv, whhZ[kt],     az0);
                anh0 = mfma(hv, wn[kt],       anh0);
                ar1  = mfma(hv, whhR[8 + kt], ar1);
                az1  = mfma(hv, whhZ[8 + kt], az1);
                anh1 = mfma(hv, wn[8 + kt],   anh1);
            }
        }
        // ---------------- gates -> h_new (bf16 into hn16) ----------------
#pragma unroll
        for (int v = 0; v < 4; ++v) {
            const int row = kg * 4 + v;
            {
                const float rg = sigmoidf_(ar0[v]);
                const float zg = sigmoidf_(az0[v]);
                const float ng = tanhf_(ani0[v] + rg * anh0[v]);
                *swz(hn16, row, g0) = f2b((1.f - zg) * ng + zg * hreg0[v]);
            }
            {
                const float rg = sigmoidf_(ar1[v]);
                const float zg = sigmoidf_(az1[v]);
                const float ng = tanhf_(ani1[v] + rg * anh1[v]);
                *swz(hn16, row, g1) = f2b((1.f - zg) * ng + zg * hreg1[v]);
            }
        }
        __syncthreads();

        // ---------------- phase 2: s_next = sig(h_new @ w_state^T) -------
        // issue x(t+1) raw loads first: latency hides under the state GEMM
        f32x4 xraw[8];
        {
            const int tn = (t + 1 < T_) ? t + 1 : t;
            const float* xr = a + ((size_t)(R0 + m) * T_ + tn) * I_ + kg * 8;
#pragma unroll
            for (int kt = 0; kt < 4; ++kt) {
                xraw[2 * kt]     = ld4(xr + kt * 32);
                xraw[2 * kt + 1] = ld4(xr + kt * 32 + 4);
            }
            PIN8(xraw);
        }
        short8 na[8];
#pragma unroll
        for (int kt = 0; kt < 8; ++kt)
            na[kt] = ldg8(swzc(hn16, m, kt * 32 + kg * 8));
        f32x4 sa0 = {0,0,0,0}, sa1 = {0,0,0,0};
#pragma unroll
        for (int kt = 0; kt < 8; ++kt) {
            sa0 = mfma(na[kt], ldg8(swzc(wst_l, g0, kt * 32 + kg * 8)), sa0);
            sa1 = mfma(na[kt], ldg8(swzc(wst_l, g1, kt * 32 + kg * 8)), sa1);
        }
#pragma unroll
        for (int v = 0; v < 4; ++v) {
            const int row = kg * 4 + v;
            const float u0 = sigmoidf_(sa0[v]);
            const float u1 = sigmoidf_(sa1[v]);
            hreg0[v] = u0; hreg1[v] = u1;
            *swz(h16, row, g0) = f2b(u0);
            *swz(h16, row, g1) = f2b(u1);
            float* dst = &out_s[((size_t)(R0 + row) * T_ + t) * H_];
            dst[g0] = u0;
            dst[g1] = u1;
        }
        if (blockIdx.x == 0 && w < 4) {   // r_t = sig(h_new[0] @ w_reward^T)
            const int o = w * 16 + m;
            f32x4 accr = {0,0,0,0};
            const unsigned short* p = w_rw + (size_t)o * H_ + kg * 8;
#pragma unroll
            for (int kt = 0; kt < 8; ++kt)
                accr = mfma(na[kt], ldg8(p + kt * 32), accr);
            if (kg == 0)
                out_r[t * OUT_ + o] = sigmoidf_(accr[0]);
        }
        // pack next step's x fragments from the prefetched raw values
#pragma unroll
        for (int kt = 0; kt < 4; ++kt)
            xa[kt] = pack8(xraw[2 * kt], xraw[2 * kt + 1]);
        __syncthreads();
    }
}

extern "C" void kernel_launch(void* const* d_in, const int* in_sizes, int n_in,
                              void* d_out, int out_size, void* d_ws, size_t ws_size,
                              hipStream_t stream) {
    const float* s0  = (const float*)d_in[0];
    const float* a   = (const float*)d_in[1];
    const float* wih = (const float*)d_in[2];
    const float* whh = (const float*)d_in[3];
    const float* wrw = (const float*)d_in[4];
    const float* wst = (const float*)d_in[5];

    unsigned short* ws16 = (unsigned short*)d_ws;
    unsigned short* wih16 = ws16;                 // 768*128  = 98304
    unsigned short* whh16 = wih16 + 98304;        // 768*256  = 196608
    unsigned short* wrw16 = whh16 + 196608;       // 64*256   = 16384
    unsigned short* wst16 = wrw16 + 16384;        // 256*256  = 65536

    cvt_w<<<98304  / (256 * 8), 256, 0, stream>>>(wih, wih16, 98304);
    cvt_w<<<196608 / (256 * 8), 256, 0, stream>>>(whh, whh16, 196608);
    cvt_w<<<16384  / (256 * 8), 256, 0, stream>>>(wrw, wrw16, 16384);
    cvt_w<<<65536  / (256 * 8), 256, 0, stream>>>(wst, wst16, 65536);

    float* out = (float*)d_out;
    gru_fused<<<NBLK, 512, 0, stream>>>(s0, a, wih16, whh16, wrw16, wst16,
                                        out, out + (size_t)T_ * OUT_);
}